// Round 1
// baseline (347.258 us; speedup 1.0000x reference)
//
#include <hip/hip_runtime.h>

#define B    64
#define K    512
#define C    4
#define NL   5
#define BK   (B*K)
#define ROWS 128            // rows of Habs2 per block
#define NT   1024           // threads per block (16 waves)
#define GRID (B*4)          // 256 blocks = 1 per CU

typedef _Float16 half_t;
typedef _Float16 half8 __attribute__((ext_vector_type(8)));
typedef float    f4    __attribute__((ext_vector_type(4)));

// ---- LDS layout (bytes) ---------------------------------------------------
#define HABS_BYTES (ROWS*K*2)            // 131072 : fp16 |H|^2 slice [128][512]
#define VST_OFF    (HABS_BYTES)          // float2[512] whole-batch v state
#define PART_OFF   (VST_OFF + K*8)       // float[8][512] cross-wave partials
#define XSQ_OFF    (PART_OFF + 8*K*4)    // float[512] whole-batch |v|^2
#define DAB_OFF    (XSQ_OFF + K*4)       // float[128] |H_jj|^2 (own rows)
#define SMEM_BYTES (DAB_OFF + ROWS*4)    // 154112 <= 160 KiB

// ---- grid-wide sense-reversing barrier (agent scope, works w/ or w/o
// cooperative launch; state zeroed by a memset node each graph replay) ------
__device__ __forceinline__ void grid_barrier(unsigned* bar) {
    __syncthreads();
    if (threadIdx.x == 0) {
        unsigned g = __hip_atomic_load(bar + 1, __ATOMIC_RELAXED,
                                       __HIP_MEMORY_SCOPE_AGENT);
        unsigned a = __hip_atomic_fetch_add(bar, 1u, __ATOMIC_ACQ_REL,
                                            __HIP_MEMORY_SCOPE_AGENT);
        if (a == GRID - 1) {
            __hip_atomic_store(bar, 0u, __ATOMIC_RELAXED,
                               __HIP_MEMORY_SCOPE_AGENT);
            __hip_atomic_store(bar + 1, g + 1u, __ATOMIC_RELEASE,
                               __HIP_MEMORY_SCOPE_AGENT);
        } else {
            while (__hip_atomic_load(bar + 1, __ATOMIC_ACQUIRE,
                                     __HIP_MEMORY_SCOPE_AGENT) == g)
                __builtin_amdgcn_s_sleep(1);
        }
    }
    __syncthreads();
}

// ---------------------------------------------------------------------------
// One persistent kernel. Block (b, q=quarter) owns rows j0..j0+127 of batch b,
// kept as fp16 in LDS for all 5 layers. Per layer:
//   P1: cov matvec (8 rows/wave, lane owns 8 cols) -> per-row u/w algebra
//   P2: transposed matvec reusing the SAME register fragments; two-pass
//       cross-wave LDS reduction; write per-quarter ul partial to global
//   grid barrier
//   FIN: whole-batch finish (redundant x4 across quarters -> xsq/vst stay
//        block-local in LDS); out written only by the owning quarter.
// Double-buffered vtilde/ulpart => one barrier per layer.
// ---------------------------------------------------------------------------
__global__ __launch_bounds__(NT, 4) void k_all(
    const float* __restrict__ hre,  const float* __restrict__ him,
    const float* __restrict__ noise,const float* __restrict__ mp,
    const float* __restrict__ vre,  const float* __restrict__ vim,
    const float* __restrict__ ar_re,const float* __restrict__ ar_im,
    const float* __restrict__ dl_re,const float* __restrict__ dl_im,
    const float* __restrict__ rc_re,const float* __restrict__ rc_im,
    float2* __restrict__ vtilde,    // [2][BK]
    float*  __restrict__ ulpart,    // [2][B*4][K]
    unsigned* __restrict__ bar,
    float* __restrict__ out)        // [NL][BK][2]
{
    extern __shared__ char smem[];
    half_t* habs = (half_t*)smem;
    float2* vst  = (float2*)(smem + VST_OFF);
    float*  part = (float*) (smem + PART_OFF);
    float*  xsq  = (float*) (smem + XSQ_OFF);
    float*  dab  = (float*) (smem + DAB_OFF);

    const int tid  = threadIdx.x;
    const int lane = tid & 63;
    const int w    = tid >> 6;
    const int b    = blockIdx.x >> 2;
    const int q    = blockIdx.x & 3;
    const int j0   = q * ROWS;

    // ---------------- load: |H|^2 slice -> LDS fp16, diag, v state ---------
    {
        const size_t gb = ((size_t)b * K + j0) * K;
        for (int i = 0; i < 8; ++i) {
            const int e = i * (NT * 8) + tid * 8;     // 0..65535
            const f4* r4 = (const f4*)(hre + gb + e);
            const f4* i4 = (const f4*)(him + gb + e);
            f4 r0 = __builtin_nontemporal_load(r4);
            f4 r1 = __builtin_nontemporal_load(r4 + 1);
            f4 m0 = __builtin_nontemporal_load(i4);
            f4 m1 = __builtin_nontemporal_load(i4 + 1);
            float s[8];
            s[0] = r0.x*r0.x + m0.x*m0.x; s[1] = r0.y*r0.y + m0.y*m0.y;
            s[2] = r0.z*r0.z + m0.z*m0.z; s[3] = r0.w*r0.w + m0.w*m0.w;
            s[4] = r1.x*r1.x + m1.x*m1.x; s[5] = r1.y*r1.y + m1.y*m1.y;
            s[6] = r1.z*r1.z + m1.z*m1.z; s[7] = r1.w*r1.w + m1.w*m1.w;
            half8 h;
#pragma unroll
            for (int t = 0; t < 8; ++t) h[t] = (_Float16)s[t];
            *(half8*)(habs + e) = h;
            const int row  = e >> 9;                  // local row 0..127
            const int col0 = e & (K - 1);
            const int j    = j0 + row;                // diag at global col j
            if (j >= col0 && j < col0 + 8) dab[row] = s[j - col0];
        }
        if (tid < K) {
            float a = vre[b * K + tid], c = vim[b * K + tid];
            vst[tid] = make_float2(a, c);
            xsq[tid] = a * a + c * c;
        }
    }
    __syncthreads();

    int buf = 0;
    for (int l = 0; l < NL; ++l) {
        // ---------------- P1: cov matvec + per-row algebra -----------------
        const f4 xa = ((const f4*)xsq)[lane * 2];
        const f4 xb = ((const f4*)xsq)[lane * 2 + 1];
        half8 h[8];
        float rs[8];
#pragma unroll
        for (int r = 0; r < 8; ++r) {
            h[r] = *(const half8*)(habs + ((w * 8 + r) * K + lane * 8));
            float acc = (float)h[r][0]*xa.x + (float)h[r][1]*xa.y +
                        (float)h[r][2]*xa.z + (float)h[r][3]*xa.w +
                        (float)h[r][4]*xb.x + (float)h[r][5]*xb.y +
                        (float)h[r][6]*xb.z + (float)h[r][7]*xb.w;
#pragma unroll
            for (int off = 32; off; off >>= 1) acc += __shfl_xor(acc, off, 64);
            rs[r] = acc;                              // all lanes hold row sum
        }
        float ulv_own = 0.f;
        if (lane < 8) {
            const int row = w * 8 + lane;
            const int j   = j0 + row;
            const int bj  = b * K + j;
            float s = lane==0?rs[0]:lane==1?rs[1]:lane==2?rs[2]:lane==3?rs[3]:
                      lane==4?rs[4]:lane==5?rs[5]:lane==6?rs[6]:rs[7];
            const float cov = s + noise[bj];
            const float d2  = dab[row];
            const float A   = d2 * xsq[j];
            const float ww  = cov / (cov - A);        // w is real, > 0
            const float sc  = d2 * ww / cov;
            const float2 vv = vst[j];
            vtilde[buf * BK + bj] = make_float2(sc * vv.x, sc * vv.y);
            ulv_own = A * ww / (cov * cov);           // |u|^2 |w|
        }
        float ulv[8];
#pragma unroll
        for (int r = 0; r < 8; ++r) ulv[r] = __shfl(ulv_own, r, 64);

        // ---------------- P2: transposed matvec, reuse h fragments ---------
        float pw[8];
#pragma unroll
        for (int t = 0; t < 8; ++t) {
            pw[t] = (float)h[0][t]*ulv[0] + (float)h[1][t]*ulv[1] +
                    (float)h[2][t]*ulv[2] + (float)h[3][t]*ulv[3] +
                    (float)h[4][t]*ulv[4] + (float)h[5][t]*ulv[5] +
                    (float)h[6][t]*ulv[6] + (float)h[7][t]*ulv[7];
        }
        float* pr = part + (w & 7) * K + lane * 8;
        if (w < 8) {
#pragma unroll
            for (int t = 0; t < 8; ++t) pr[t] = pw[t];
        }
        __syncthreads();
        if (w >= 8) {
#pragma unroll
            for (int t = 0; t < 8; ++t) pr[t] += pw[t];  // disjoint slots
        }
        __syncthreads();
        if (tid < K) {
            float s2 = part[tid]       + part[K + tid]   + part[2*K + tid] +
                       part[3*K + tid] + part[4*K + tid] + part[5*K + tid] +
                       part[6*K + tid] + part[7*K + tid];
            ulpart[(size_t)buf * (B*4*K) + (size_t)blockIdx.x * K + tid] = s2;
        }
        grid_barrier(bar);

        // ---------------- FIN: whole batch row (redundant x4) --------------
        if (tid < K) {
            const int k  = tid;
            const int bk = b * K + k;
            const float* up = ulpart + (size_t)buf * (B*4*K) + (size_t)(b*4) * K;
            float ul = up[k] + up[K + k] + up[2*K + k] + up[3*K + k];
            const float2 vt = vtilde[buf * BK + bk];
            const float p   = mp[bk];
            const float avt = sqrtf(vt.x*vt.x + vt.y*vt.y);
            const float mu  = fmaxf(avt / sqrtf(p) - ul, 0.f);
            const float inv = 1.f / (ul + mu);
            float ax = 0.f, ay = 0.f;
#pragma unroll
            for (int c = 0; c < C; ++c) {
                const float gre = ar_re[c] * inv + dl_re[c];
                const float gim = ar_im[c] * inv + dl_im[c];
                float zre = vt.x * gre - vt.y * gim;
                float zim = vt.x * gim + vt.y * gre;
                zre = fmaxf(zre, 0.f);                 // CReLU
                zim = fmaxf(zim, 0.f);
                ax += zre * rc_re[c] - zim * rc_im[c];
                ay += zre * rc_im[c] + zim * rc_re[c];
            }
            const float n2   = ax*ax + ay*ay;
            const float cur  = fmaxf(p, n2);
            const float corr = fminf(sqrtf(p / cur), 1.f);
            ax *= corr; ay *= corr;
            if ((k >> 7) == q)                          // owner writes out
                ((float2*)out)[(size_t)l * BK + bk] = make_float2(ax, ay);
            vst[k] = make_float2(ax, ay);
            xsq[k] = ax * ax + ay * ay;
        }
        __syncthreads();
        buf ^= 1;
    }
}

// ---------------------------------------------------------------------------
extern "C" void kernel_launch(void* const* d_in, const int* in_sizes, int n_in,
                              void* d_out, int out_size, void* d_ws, size_t ws_size,
                              hipStream_t stream) {
    const float* hre   = (const float*)d_in[0];
    const float* him   = (const float*)d_in[1];
    const float* noise = (const float*)d_in[2];
    const float* mp    = (const float*)d_in[3];
    const float* vre   = (const float*)d_in[4];
    const float* vim   = (const float*)d_in[5];
    const float* ar_re = (const float*)d_in[6];
    const float* ar_im = (const float*)d_in[7];
    const float* dl_re = (const float*)d_in[8];
    const float* dl_im = (const float*)d_in[9];
    const float* rc_re = (const float*)d_in[10];
    const float* rc_im = (const float*)d_in[11];
    float* out = (float*)d_out;

    char*     ws     = (char*)d_ws;
    float2*   vtilde = (float2*)ws;                               // 512 KB
    float*    ulpart = (float*)(ws + 2*(size_t)BK*8);             // 1 MB
    unsigned* bar    = (unsigned*)(ws + 2*(size_t)BK*8 + 2*(size_t)B*4*K*4);

    static bool attr_done = false;
    if (!attr_done) {
        hipFuncSetAttribute((const void*)k_all,
                            hipFuncAttributeMaxDynamicSharedMemorySize,
                            SMEM_BYTES);
        attr_done = true;
    }

    // barrier state must be zero at kernel start on every graph replay
    hipMemsetAsync(bar, 0, 64, stream);

    void* args[] = { &hre, &him, &noise, &mp, &vre, &vim,
                     &ar_re, &ar_im, &dl_re, &dl_im, &rc_re, &rc_im,
                     &vtilde, &ulpart, &bar, &out };
    hipError_t err = hipLaunchCooperativeKernel((const void*)k_all,
                                                dim3(GRID), dim3(NT),
                                                (void**)args, SMEM_BYTES, stream);
    if (err != hipSuccess) {
        // custom barrier does not depend on cooperative launch; 256 blocks at
        // 1 block/CU (LDS-pinned) are co-resident on 256 CUs.
        (void)hipGetLastError();
        hipLaunchKernelGGL(k_all, dim3(GRID), dim3(NT), SMEM_BYTES, stream,
                           hre, him, noise, mp, vre, vim,
                           ar_re, ar_im, dl_re, dl_im, rc_re, rc_im,
                           vtilde, ulpart, bar, out);
    }
}

// Round 2
// 252.744 us; speedup vs baseline: 1.3740x; 1.3740x over previous
//
#include <hip/hip_runtime.h>

#define B    64
#define K    512
#define C    4
#define NL   5
#define BK   (B*K)
#define ROWS 128            // rows of Habs2 per block
#define NT   1024           // threads per block (16 waves)
#define GRID (B*4)          // 256 blocks = 1 per CU

typedef _Float16 half_t;
typedef _Float16 half8 __attribute__((ext_vector_type(8)));
typedef float    f4    __attribute__((ext_vector_type(4)));

// ---- LDS layout (bytes) ---------------------------------------------------
#define HABS_BYTES (ROWS*K*2)            // 131072 : fp16 |H|^2 slice [128][512]
#define VST_OFF    (HABS_BYTES)          // float2[512] whole-batch v state
#define PART_OFF   (VST_OFF + K*8)       // float[8][512] cross-wave partials
#define XSQ_OFF    (PART_OFF + 8*K*4)    // float[512] whole-batch |v|^2
#define DAB_OFF    (XSQ_OFF + K*4)       // float[128] |H_jj|^2 (own rows)
#define SMEM_BYTES (DAB_OFF + ROWS*4)    // 154112 <= 160 KiB

// ---- quartet barrier: only the 4 blocks sharing batch b sync --------------
// qb[0]=arrival count, qb[1]=generation; one 128-B line per quartet.
__device__ __forceinline__ void quartet_barrier(unsigned* qb) {
    __syncthreads();
    if (threadIdx.x == 0) {
        unsigned g = __hip_atomic_load(qb + 1, __ATOMIC_RELAXED,
                                       __HIP_MEMORY_SCOPE_AGENT);
        unsigned a = __hip_atomic_fetch_add(qb, 1u, __ATOMIC_ACQ_REL,
                                            __HIP_MEMORY_SCOPE_AGENT);
        if (a == 3u) {
            __hip_atomic_store(qb, 0u, __ATOMIC_RELAXED,
                               __HIP_MEMORY_SCOPE_AGENT);
            __hip_atomic_store(qb + 1, g + 1u, __ATOMIC_RELEASE,
                               __HIP_MEMORY_SCOPE_AGENT);
        } else {
            while (__hip_atomic_load(qb + 1, __ATOMIC_ACQUIRE,
                                     __HIP_MEMORY_SCOPE_AGENT) == g)
                __builtin_amdgcn_s_sleep(2);
        }
    }
    __syncthreads();
}

// ---------------------------------------------------------------------------
// One persistent kernel. Block (b, q) owns rows j0..j0+127 of batch b in LDS
// (fp16) for all 5 layers. Per layer: P1 cov matvec -> per-row algebra; P2
// transposed matvec reusing register fragments; quartet barrier; FIN whole
// batch (redundant x4 so vst/xsq stay block-local). Double-buffered
// vtilde/ulpart => one quartet barrier per layer.
// ---------------------------------------------------------------------------
__global__ __launch_bounds__(NT, 4) void k_all(
    const float* __restrict__ hre,  const float* __restrict__ him,
    const float* __restrict__ noise,const float* __restrict__ mp,
    const float* __restrict__ vre,  const float* __restrict__ vim,
    const float* __restrict__ ar_re,const float* __restrict__ ar_im,
    const float* __restrict__ dl_re,const float* __restrict__ dl_im,
    const float* __restrict__ rc_re,const float* __restrict__ rc_im,
    float2* __restrict__ vtilde,    // [2][BK]
    float*  __restrict__ ulpart,    // [2][B*4][K]
    unsigned* __restrict__ bar,     // 64 quartets x 32 uints (128 B)
    float* __restrict__ out)        // [NL][BK][2]
{
    extern __shared__ char smem[];
    half_t* habs = (half_t*)smem;
    float2* vst  = (float2*)(smem + VST_OFF);
    float*  part = (float*) (smem + PART_OFF);
    float*  xsq  = (float*) (smem + XSQ_OFF);
    float*  dab  = (float*) (smem + DAB_OFF);

    const int tid  = threadIdx.x;
    const int lane = tid & 63;
    const int w    = tid >> 6;
    const int b    = blockIdx.x >> 2;
    const int q    = blockIdx.x & 3;
    const int j0   = q * ROWS;
    unsigned* qb   = bar + ((unsigned)b << 5);

    // ---------------- load: |H|^2 slice -> LDS fp16 (depth-2 pipeline) -----
    {
        const size_t gb = ((size_t)b * K + j0) * K;
        const f4* rp = (const f4*)(hre + gb);
        const f4* ip = (const f4*)(him + gb);
        f4 lr0[2], lr1[2], li0[2], li1[2];
        lr0[0] = __builtin_nontemporal_load(rp + tid * 2);
        lr1[0] = __builtin_nontemporal_load(rp + tid * 2 + 1);
        li0[0] = __builtin_nontemporal_load(ip + tid * 2);
        li1[0] = __builtin_nontemporal_load(ip + tid * 2 + 1);
#pragma unroll
        for (int i = 0; i < 8; ++i) {
            const int cur = i & 1, nxt = cur ^ 1;
            if (i < 7) {
                const int e4 = (i + 1) * (NT * 2) + tid * 2;
                lr0[nxt] = __builtin_nontemporal_load(rp + e4);
                lr1[nxt] = __builtin_nontemporal_load(rp + e4 + 1);
                li0[nxt] = __builtin_nontemporal_load(ip + e4);
                li1[nxt] = __builtin_nontemporal_load(ip + e4 + 1);
            }
            const f4 r0 = lr0[cur], r1 = lr1[cur];
            const f4 m0 = li0[cur], m1 = li1[cur];
            float s[8];
            s[0] = r0.x*r0.x + m0.x*m0.x; s[1] = r0.y*r0.y + m0.y*m0.y;
            s[2] = r0.z*r0.z + m0.z*m0.z; s[3] = r0.w*r0.w + m0.w*m0.w;
            s[4] = r1.x*r1.x + m1.x*m1.x; s[5] = r1.y*r1.y + m1.y*m1.y;
            s[6] = r1.z*r1.z + m1.z*m1.z; s[7] = r1.w*r1.w + m1.w*m1.w;
            half8 hh;
#pragma unroll
            for (int t = 0; t < 8; ++t) hh[t] = (_Float16)s[t];
            const int e = i * (NT * 8) + tid * 8;     // element 0..65535
            *(half8*)(habs + e) = hh;
            const int row  = e >> 9;                  // local row 0..127
            const int col0 = e & (K - 1);
            const int j    = j0 + row;                // diag at global col j
            if (j >= col0 && j < col0 + 8) dab[row] = s[j - col0];
        }
        if (tid < K) {
            float a = vre[b * K + tid], c = vim[b * K + tid];
            vst[tid] = make_float2(a, c);
            xsq[tid] = a * a + c * c;
        }
    }
    __syncthreads();

    int buf = 0;
    for (int l = 0; l < NL; ++l) {
        // ---------------- P1: cov matvec + per-row algebra -----------------
        const f4 xa = ((const f4*)xsq)[lane * 2];
        const f4 xb = ((const f4*)xsq)[lane * 2 + 1];
        half8 h[8];
        float rs[8];
#pragma unroll
        for (int r = 0; r < 8; ++r) {
            h[r] = *(const half8*)(habs + ((w * 8 + r) * K + lane * 8));
            float acc = (float)h[r][0]*xa.x + (float)h[r][1]*xa.y +
                        (float)h[r][2]*xa.z + (float)h[r][3]*xa.w +
                        (float)h[r][4]*xb.x + (float)h[r][5]*xb.y +
                        (float)h[r][6]*xb.z + (float)h[r][7]*xb.w;
#pragma unroll
            for (int off = 32; off; off >>= 1) acc += __shfl_xor(acc, off, 64);
            rs[r] = acc;                              // all lanes hold row sum
        }
        float ulv_own = 0.f;
        if (lane < 8) {
            const int row = w * 8 + lane;
            const int j   = j0 + row;
            const int bj  = b * K + j;
            float s = lane==0?rs[0]:lane==1?rs[1]:lane==2?rs[2]:lane==3?rs[3]:
                      lane==4?rs[4]:lane==5?rs[5]:lane==6?rs[6]:rs[7];
            const float cov = s + noise[bj];
            const float d2  = dab[row];
            const float A   = d2 * xsq[j];
            const float ww  = cov / (cov - A);        // w is real, > 0
            const float sc  = d2 * ww / cov;
            const float2 vv = vst[j];
            vtilde[buf * BK + bj] = make_float2(sc * vv.x, sc * vv.y);
            ulv_own = A * ww / (cov * cov);           // |u|^2 |w|
        }
        float ulv[8];
#pragma unroll
        for (int r = 0; r < 8; ++r) ulv[r] = __shfl(ulv_own, r, 64);

        // ---------------- P2: transposed matvec, reuse h fragments ---------
        float pw[8];
#pragma unroll
        for (int t = 0; t < 8; ++t) {
            pw[t] = (float)h[0][t]*ulv[0] + (float)h[1][t]*ulv[1] +
                    (float)h[2][t]*ulv[2] + (float)h[3][t]*ulv[3] +
                    (float)h[4][t]*ulv[4] + (float)h[5][t]*ulv[5] +
                    (float)h[6][t]*ulv[6] + (float)h[7][t]*ulv[7];
        }
        float* pr = part + (w & 7) * K + lane * 8;
        if (w < 8) {
#pragma unroll
            for (int t = 0; t < 8; ++t) pr[t] = pw[t];
        }
        __syncthreads();
        if (w >= 8) {
#pragma unroll
            for (int t = 0; t < 8; ++t) pr[t] += pw[t];  // disjoint slots
        }
        __syncthreads();
        if (tid < K) {
            float s2 = part[tid]       + part[K + tid]   + part[2*K + tid] +
                       part[3*K + tid] + part[4*K + tid] + part[5*K + tid] +
                       part[6*K + tid] + part[7*K + tid];
            ulpart[(size_t)buf * (B*4*K) + (size_t)blockIdx.x * K + tid] = s2;
        }
        quartet_barrier(qb);

        // ---------------- FIN: whole batch row (redundant x4) --------------
        if (tid < K) {
            const int k  = tid;
            const int bk = b * K + k;
            const float* up = ulpart + (size_t)buf * (B*4*K) + (size_t)(b*4) * K;
            float ul = up[k] + up[K + k] + up[2*K + k] + up[3*K + k];
            const float2 vt = vtilde[buf * BK + bk];
            const float p   = mp[bk];
            const float avt = sqrtf(vt.x*vt.x + vt.y*vt.y);
            const float mu  = fmaxf(avt / sqrtf(p) - ul, 0.f);
            const float inv = 1.f / (ul + mu);
            float ax = 0.f, ay = 0.f;
#pragma unroll
            for (int c = 0; c < C; ++c) {
                const float gre = ar_re[c] * inv + dl_re[c];
                const float gim = ar_im[c] * inv + dl_im[c];
                float zre = vt.x * gre - vt.y * gim;
                float zim = vt.x * gim + vt.y * gre;
                zre = fmaxf(zre, 0.f);                 // CReLU
                zim = fmaxf(zim, 0.f);
                ax += zre * rc_re[c] - zim * rc_im[c];
                ay += zre * rc_im[c] + zim * rc_re[c];
            }
            const float n2   = ax*ax + ay*ay;
            const float cur  = fmaxf(p, n2);
            const float corr = fminf(sqrtf(p / cur), 1.f);
            ax *= corr; ay *= corr;
            if ((k >> 7) == q)                          // owner writes out
                ((float2*)out)[(size_t)l * BK + bk] = make_float2(ax, ay);
            vst[k] = make_float2(ax, ay);
            xsq[k] = ax * ax + ay * ay;
        }
        __syncthreads();
        buf ^= 1;
    }
}

// ---------------------------------------------------------------------------
extern "C" void kernel_launch(void* const* d_in, const int* in_sizes, int n_in,
                              void* d_out, int out_size, void* d_ws, size_t ws_size,
                              hipStream_t stream) {
    const float* hre   = (const float*)d_in[0];
    const float* him   = (const float*)d_in[1];
    const float* noise = (const float*)d_in[2];
    const float* mp    = (const float*)d_in[3];
    const float* vre   = (const float*)d_in[4];
    const float* vim   = (const float*)d_in[5];
    const float* ar_re = (const float*)d_in[6];
    const float* ar_im = (const float*)d_in[7];
    const float* dl_re = (const float*)d_in[8];
    const float* dl_im = (const float*)d_in[9];
    const float* rc_re = (const float*)d_in[10];
    const float* rc_im = (const float*)d_in[11];
    float* out = (float*)d_out;

    char*     ws     = (char*)d_ws;
    float2*   vtilde = (float2*)ws;                               // 512 KB
    float*    ulpart = (float*)(ws + 2*(size_t)BK*8);             // 1 MB
    unsigned* bar    = (unsigned*)(ws + 2*(size_t)BK*8 + 2*(size_t)B*4*K*4);

    static bool attr_done = false;
    if (!attr_done) {
        hipFuncSetAttribute((const void*)k_all,
                            hipFuncAttributeMaxDynamicSharedMemorySize,
                            SMEM_BYTES);
        attr_done = true;
    }

    // per-quartet barrier state must be zero at kernel start on every replay
    hipMemsetAsync(bar, 0, B * 32 * sizeof(unsigned), stream);

    // plain launch: 256 blocks at 1 block/CU (LDS-pinned) are co-resident,
    // and the barrier is quartet-scoped anyway.
    hipLaunchKernelGGL(k_all, dim3(GRID), dim3(NT), SMEM_BYTES, stream,
                       hre, him, noise, mp, vre, vim,
                       ar_re, ar_im, dl_re, dl_im, rc_re, rc_im,
                       vtilde, ulpart, bar, out);
}

// Round 3
// 221.207 us; speedup vs baseline: 1.5698x; 1.1426x over previous
//
#include <hip/hip_runtime.h>

#define B    64
#define K    512
#define C    4
#define NL   5
#define BK   (B*K)
#define ROWS 128            // rows of Habs2 per block
#define NT   1024           // threads per block (16 waves)
#define GRID (B*4)          // 256 blocks = 1 per CU

typedef _Float16 half_t;
typedef _Float16 half8 __attribute__((ext_vector_type(8)));
typedef float    f4    __attribute__((ext_vector_type(4)));

// ---- LDS layout (bytes) ---------------------------------------------------
#define HABS_BYTES (ROWS*K*2)            // 131072 : fp16 |H|^2 slice [128][512]
#define VST_OFF    (HABS_BYTES)          // float2[512] whole-batch v state
#define PART_OFF   (VST_OFF + K*8)       // float[8][512] cross-wave partials
#define XSQ_OFF    (PART_OFF + 8*K*4)    // float[512] whole-batch |v|^2
#define DAB_OFF    (XSQ_OFF + K*4)       // float[128] |H_jj|^2 (own rows)
#define MPL_OFF    (DAB_OFF + ROWS*4)    // float[512] maxpow (whole batch)
#define NZ_OFF     (MPL_OFF + K*4)       // float[128] noise (own rows)
#define SMEM_BYTES (NZ_OFF + ROWS*4)     // 156672 <= 160 KiB

// ---- quartet barrier: 4 blocks sharing batch b -----------------------------
// qb[0]=count, qb[1]=generation. RELAXED polling (no per-poll L2 invalidate);
// one acquire fence on exit. fetch_add(ACQ_REL) releases prior stores.
__device__ __forceinline__ void quartet_barrier(unsigned* qb) {
    __syncthreads();
    if (threadIdx.x == 0) {
        unsigned g = __hip_atomic_load(qb + 1, __ATOMIC_RELAXED,
                                       __HIP_MEMORY_SCOPE_AGENT);
        unsigned a = __hip_atomic_fetch_add(qb, 1u, __ATOMIC_ACQ_REL,
                                            __HIP_MEMORY_SCOPE_AGENT);
        if (a == 3u) {
            __hip_atomic_store(qb, 0u, __ATOMIC_RELAXED,
                               __HIP_MEMORY_SCOPE_AGENT);
            __hip_atomic_store(qb + 1, g + 1u, __ATOMIC_RELEASE,
                               __HIP_MEMORY_SCOPE_AGENT);
        } else {
            while (__hip_atomic_load(qb + 1, __ATOMIC_RELAXED,
                                     __HIP_MEMORY_SCOPE_AGENT) == g)
                __builtin_amdgcn_s_sleep(2);
            __builtin_amdgcn_fence(__ATOMIC_ACQUIRE, "agent");
        }
    }
    __syncthreads();
}

// ---------------------------------------------------------------------------
// One persistent kernel. Block (b, q) owns rows j0..j0+127 of batch b in LDS
// (fp16) for all 5 layers. XCD-local quartets: b = blockIdx&63, q = blockIdx>>6
// puts the 4 quartet members at blockIdx ≡ b (mod 8) -> same XCD under
// round-robin dispatch (perf heuristic only). Per layer: P1 cov matvec ->
// per-row algebra; P2 transposed matvec reusing register fragments; quartet
// barrier; FIN whole batch (redundant x4 so vst/xsq stay block-local).
// ---------------------------------------------------------------------------
__global__ __launch_bounds__(NT, 4) void k_all(
    const float* __restrict__ hre,  const float* __restrict__ him,
    const float* __restrict__ noise,const float* __restrict__ mp,
    const float* __restrict__ vre,  const float* __restrict__ vim,
    const float* __restrict__ ar_re,const float* __restrict__ ar_im,
    const float* __restrict__ dl_re,const float* __restrict__ dl_im,
    const float* __restrict__ rc_re,const float* __restrict__ rc_im,
    float2* __restrict__ vtilde,    // [2][BK]
    float*  __restrict__ ulpart,    // [2][B*4][K]
    unsigned* __restrict__ bar,     // 64 quartets x 32 uints (128 B)
    float* __restrict__ out)        // [NL][BK][2]
{
    extern __shared__ char smem[];
    half_t* habs = (half_t*)smem;
    float2* vst  = (float2*)(smem + VST_OFF);
    float*  part = (float*) (smem + PART_OFF);
    float*  xsq  = (float*) (smem + XSQ_OFF);
    float*  dab  = (float*) (smem + DAB_OFF);
    float*  mpl  = (float*) (smem + MPL_OFF);
    float*  nz   = (float*) (smem + NZ_OFF);

    const int tid  = threadIdx.x;
    const int lane = tid & 63;
    const int w    = tid >> 6;
    const int b    = blockIdx.x & 63;          // XCD-local quartet mapping
    const int q    = blockIdx.x >> 6;
    const int j0   = q * ROWS;
    unsigned* qb   = bar + ((unsigned)b << 5);

    // ---------------- load: |H|^2 slice -> LDS fp16 (depth-2 pipeline) -----
    {
        const size_t gb = ((size_t)b * K + j0) * K;
        const f4* rp = (const f4*)(hre + gb);
        const f4* ip = (const f4*)(him + gb);
        f4 lr0[2], lr1[2], li0[2], li1[2];
        lr0[0] = __builtin_nontemporal_load(rp + tid * 2);
        lr1[0] = __builtin_nontemporal_load(rp + tid * 2 + 1);
        li0[0] = __builtin_nontemporal_load(ip + tid * 2);
        li1[0] = __builtin_nontemporal_load(ip + tid * 2 + 1);
#pragma unroll
        for (int i = 0; i < 8; ++i) {
            const int cur = i & 1, nxt = cur ^ 1;
            if (i < 7) {
                const int e4 = (i + 1) * (NT * 2) + tid * 2;
                lr0[nxt] = __builtin_nontemporal_load(rp + e4);
                lr1[nxt] = __builtin_nontemporal_load(rp + e4 + 1);
                li0[nxt] = __builtin_nontemporal_load(ip + e4);
                li1[nxt] = __builtin_nontemporal_load(ip + e4 + 1);
            }
            const f4 r0 = lr0[cur], r1 = lr1[cur];
            const f4 m0 = li0[cur], m1 = li1[cur];
            float s[8];
            s[0] = r0.x*r0.x + m0.x*m0.x; s[1] = r0.y*r0.y + m0.y*m0.y;
            s[2] = r0.z*r0.z + m0.z*m0.z; s[3] = r0.w*r0.w + m0.w*m0.w;
            s[4] = r1.x*r1.x + m1.x*m1.x; s[5] = r1.y*r1.y + m1.y*m1.y;
            s[6] = r1.z*r1.z + m1.z*m1.z; s[7] = r1.w*r1.w + m1.w*m1.w;
            half8 hh;
#pragma unroll
            for (int t = 0; t < 8; ++t) hh[t] = (_Float16)s[t];
            const int e = i * (NT * 8) + tid * 8;     // element 0..65535
            *(half8*)(habs + e) = hh;
            const int row  = e >> 9;                  // local row 0..127
            const int col0 = e & (K - 1);
            const int j    = j0 + row;                // diag at global col j
            if (j >= col0 && j < col0 + 8) dab[row] = s[j - col0];
        }
        if (tid < K) {
            float a = vre[b * K + tid], c = vim[b * K + tid];
            vst[tid] = make_float2(a, c);
            xsq[tid] = a * a + c * c;
            mpl[tid] = mp[b * K + tid];
        } else if (tid < K + ROWS) {
            nz[tid - K] = noise[b * K + j0 + (tid - K)];
        }
    }
    __syncthreads();

    int buf = 0;
    for (int l = 0; l < NL; ++l) {
        // ---------------- P1: cov matvec + per-row algebra -----------------
        const f4 xa = ((const f4*)xsq)[lane * 2];
        const f4 xb = ((const f4*)xsq)[lane * 2 + 1];
        half8 h[8];
        float rs[8];
#pragma unroll
        for (int r = 0; r < 8; ++r) {
            h[r] = *(const half8*)(habs + ((w * 8 + r) * K + lane * 8));
            float acc = (float)h[r][0]*xa.x + (float)h[r][1]*xa.y +
                        (float)h[r][2]*xa.z + (float)h[r][3]*xa.w +
                        (float)h[r][4]*xb.x + (float)h[r][5]*xb.y +
                        (float)h[r][6]*xb.z + (float)h[r][7]*xb.w;
#pragma unroll
            for (int off = 32; off; off >>= 1) acc += __shfl_xor(acc, off, 64);
            rs[r] = acc;                              // all lanes hold row sum
        }
        float ulv_own = 0.f;
        if (lane < 8) {
            const int row = w * 8 + lane;
            const int j   = j0 + row;
            const int bj  = b * K + j;
            float s = lane==0?rs[0]:lane==1?rs[1]:lane==2?rs[2]:lane==3?rs[3]:
                      lane==4?rs[4]:lane==5?rs[5]:lane==6?rs[6]:rs[7];
            const float cov = s + nz[row];
            const float d2  = dab[row];
            const float A   = d2 * xsq[j];
            const float ww  = cov / (cov - A);        // w is real, > 0
            const float sc  = d2 * ww / cov;
            const float2 vv = vst[j];
            vtilde[buf * BK + bj] = make_float2(sc * vv.x, sc * vv.y);
            ulv_own = A * ww / (cov * cov);           // |u|^2 |w|
        }
        float ulv[8];
#pragma unroll
        for (int r = 0; r < 8; ++r) ulv[r] = __shfl(ulv_own, r, 64);

        // ---------------- P2: transposed matvec, reuse h fragments ---------
        float pw[8];
#pragma unroll
        for (int t = 0; t < 8; ++t) {
            pw[t] = (float)h[0][t]*ulv[0] + (float)h[1][t]*ulv[1] +
                    (float)h[2][t]*ulv[2] + (float)h[3][t]*ulv[3] +
                    (float)h[4][t]*ulv[4] + (float)h[5][t]*ulv[5] +
                    (float)h[6][t]*ulv[6] + (float)h[7][t]*ulv[7];
        }
        float* pr = part + (w & 7) * K + lane * 8;
        if (w < 8) {
#pragma unroll
            for (int t = 0; t < 8; ++t) pr[t] = pw[t];
        }
        __syncthreads();
        if (w >= 8) {
#pragma unroll
            for (int t = 0; t < 8; ++t) pr[t] += pw[t];  // disjoint slots
        }
        __syncthreads();
        if (tid < K) {
            float s2 = part[tid]       + part[K + tid]   + part[2*K + tid] +
                       part[3*K + tid] + part[4*K + tid] + part[5*K + tid] +
                       part[6*K + tid] + part[7*K + tid];
            ulpart[(size_t)buf * (B*4*K) + ((size_t)(b*4 + q)) * K + tid] = s2;
        }
        quartet_barrier(qb);

        // ---------------- FIN: whole batch row (redundant x4) --------------
        if (tid < K) {
            const int k  = tid;
            const int bk = b * K + k;
            const float* up = ulpart + (size_t)buf * (B*4*K) + (size_t)(b*4) * K;
            float ul = up[k] + up[K + k] + up[2*K + k] + up[3*K + k];
            const float2 vt = vtilde[buf * BK + bk];
            const float p   = mpl[k];
            const float avt = sqrtf(vt.x*vt.x + vt.y*vt.y);
            const float mu  = fmaxf(avt / sqrtf(p) - ul, 0.f);
            const float inv = 1.f / (ul + mu);
            float ax = 0.f, ay = 0.f;
#pragma unroll
            for (int c = 0; c < C; ++c) {
                const float gre = ar_re[c] * inv + dl_re[c];
                const float gim = ar_im[c] * inv + dl_im[c];
                float zre = vt.x * gre - vt.y * gim;
                float zim = vt.x * gim + vt.y * gre;
                zre = fmaxf(zre, 0.f);                 // CReLU
                zim = fmaxf(zim, 0.f);
                ax += zre * rc_re[c] - zim * rc_im[c];
                ay += zre * rc_im[c] + zim * rc_re[c];
            }
            const float n2   = ax*ax + ay*ay;
            const float cur  = fmaxf(p, n2);
            const float corr = fminf(sqrtf(p / cur), 1.f);
            ax *= corr; ay *= corr;
            if ((k >> 7) == q)                          // owner writes out
                ((float2*)out)[(size_t)l * BK + bk] = make_float2(ax, ay);
            vst[k] = make_float2(ax, ay);
            xsq[k] = ax * ax + ay * ay;
        }
        __syncthreads();
        buf ^= 1;
    }
}

// ---------------------------------------------------------------------------
extern "C" void kernel_launch(void* const* d_in, const int* in_sizes, int n_in,
                              void* d_out, int out_size, void* d_ws, size_t ws_size,
                              hipStream_t stream) {
    const float* hre   = (const float*)d_in[0];
    const float* him   = (const float*)d_in[1];
    const float* noise = (const float*)d_in[2];
    const float* mp    = (const float*)d_in[3];
    const float* vre   = (const float*)d_in[4];
    const float* vim   = (const float*)d_in[5];
    const float* ar_re = (const float*)d_in[6];
    const float* ar_im = (const float*)d_in[7];
    const float* dl_re = (const float*)d_in[8];
    const float* dl_im = (const float*)d_in[9];
    const float* rc_re = (const float*)d_in[10];
    const float* rc_im = (const float*)d_in[11];
    float* out = (float*)d_out;

    char*     ws     = (char*)d_ws;
    float2*   vtilde = (float2*)ws;                               // 512 KB
    float*    ulpart = (float*)(ws + 2*(size_t)BK*8);             // 1 MB
    unsigned* bar    = (unsigned*)(ws + 2*(size_t)BK*8 + 2*(size_t)B*4*K*4);

    static bool attr_done = false;
    if (!attr_done) {
        hipFuncSetAttribute((const void*)k_all,
                            hipFuncAttributeMaxDynamicSharedMemorySize,
                            SMEM_BYTES);
        attr_done = true;
    }

    // per-quartet barrier state must be zero at kernel start on every replay
    hipMemsetAsync(bar, 0, B * 32 * sizeof(unsigned), stream);

    hipLaunchKernelGGL(k_all, dim3(GRID), dim3(NT), SMEM_BYTES, stream,
                       hre, him, noise, mp, vre, vim,
                       ar_re, ar_im, dl_re, dl_im, rc_re, rc_im,
                       vtilde, ulpart, bar, out);
}

// Round 4
// 192.761 us; speedup vs baseline: 1.8015x; 1.1476x over previous
//
#include <hip/hip_runtime.h>

#define B    64
#define K    512
#define C    4
#define NL   5
#define BK   (B*K)
#define ROWS 128            // rows of Habs2 per block
#define NT   1024           // threads per block (16 waves)
#define GRID (B*4)          // 256 blocks = 1 per CU

typedef _Float16 half_t;
typedef _Float16 half8 __attribute__((ext_vector_type(8)));
typedef float    f4    __attribute__((ext_vector_type(4)));

// ---- LDS layout (bytes) ---------------------------------------------------
#define HABS_BYTES (ROWS*K*2)            // 131072 : fp16 |H|^2 slice [128][512]
#define VST_OFF    (HABS_BYTES)          // float2[512] whole-batch v state
#define PART_OFF   (VST_OFF + K*8)       // float[8][512] cross-wave partials
#define XSQ_OFF    (PART_OFF + 8*K*4)    // float[512] whole-batch |v|^2
#define DAB_OFF    (XSQ_OFF + K*4)       // float[128] |H_jj|^2 (own rows)
#define MPL_OFF    (DAB_OFF + ROWS*4)    // float[512] maxpow (whole batch)
#define NZ_OFF     (MPL_OFF + K*4)       // float[128] noise (own rows)
#define SMEM_BYTES (NZ_OFF + ROWS*4)     // 156672 <= 160 KiB

// ---- L3-direct (sc1, L1/L2-bypass) data ops: relaxed agent-scope atomics ---
// No fences attach to these -> no buffer_wbl2 / buffer_inv L2 walks, and the
// data is globally visible at the coherence point (L3) immediately.
__device__ __forceinline__ float ld_l3(const float* p) {
    return __uint_as_float(__hip_atomic_load((const unsigned*)p,
        __ATOMIC_RELAXED, __HIP_MEMORY_SCOPE_AGENT));
}
__device__ __forceinline__ void st_l3(float* p, float v) {
    __hip_atomic_store((unsigned*)p, __float_as_uint(v),
        __ATOMIC_RELAXED, __HIP_MEMORY_SCOPE_AGENT);
}
__device__ __forceinline__ void st_l3_2(float2* p, float2 v) {
    unsigned long long u = ((unsigned long long)__float_as_uint(v.y) << 32)
                         | (unsigned long long)__float_as_uint(v.x);
    __hip_atomic_store((unsigned long long*)p, u,
        __ATOMIC_RELAXED, __HIP_MEMORY_SCOPE_AGENT);
}
__device__ __forceinline__ float2 ld_l3_2(const float2* p) {
    unsigned long long u = __hip_atomic_load((const unsigned long long*)p,
        __ATOMIC_RELAXED, __HIP_MEMORY_SCOPE_AGENT);
    return make_float2(__uint_as_float((unsigned)(u & 0xffffffffu)),
                       __uint_as_float((unsigned)(u >> 32)));
}

// ---- fence-free quartet barrier: monotonic counter, fully relaxed ----------
// Correctness: __syncthreads drains vmcnt(0) before s_barrier (compiler-
// guaranteed), so every sc1 data store of this block is at L3 before the
// arrival increment. Seeing ctr >= 4*phase therefore implies all 4 blocks'
// sc1 data is L3-visible; subsequent sc1 loads read it. No reset store, so
// no store-ordering hazard; counter is zeroed per replay by memsetAsync.
__device__ __forceinline__ void quartet_barrier(unsigned* qb, unsigned target) {
    __syncthreads();
    if (threadIdx.x == 0) {
        __hip_atomic_fetch_add(qb, 1u, __ATOMIC_RELAXED,
                               __HIP_MEMORY_SCOPE_AGENT);
        while (__hip_atomic_load(qb, __ATOMIC_RELAXED,
                                 __HIP_MEMORY_SCOPE_AGENT) < target)
            __builtin_amdgcn_s_sleep(4);
    }
    __syncthreads();
}

// ---------------------------------------------------------------------------
// One persistent kernel. Block (b, q) owns rows j0..j0+127 of batch b in LDS
// (fp16) for all 5 layers. b = blockIdx&63, q = blockIdx>>6 puts quartet
// members at blockIdx ≡ b (mod 8) -> same XCD under round-robin dispatch
// (perf heuristic only). Per layer: P1 cov matvec -> per-row algebra; P2
// transposed matvec reusing register fragments; fence-free quartet barrier;
// FIN whole batch (redundant x4 so vst/xsq stay block-local). Cross-block
// data moves via L3-direct sc1 ops only.
// ---------------------------------------------------------------------------
__global__ __launch_bounds__(NT, 4) void k_all(
    const float* __restrict__ hre,  const float* __restrict__ him,
    const float* __restrict__ noise,const float* __restrict__ mp,
    const float* __restrict__ vre,  const float* __restrict__ vim,
    const float* __restrict__ ar_re,const float* __restrict__ ar_im,
    const float* __restrict__ dl_re,const float* __restrict__ dl_im,
    const float* __restrict__ rc_re,const float* __restrict__ rc_im,
    float2* __restrict__ vtilde,    // [2][BK]
    float*  __restrict__ ulpart,    // [2][B*4][K]
    unsigned* __restrict__ bar,     // 64 quartets x 32 uints (128 B)
    float* __restrict__ out)        // [NL][BK][2]
{
    extern __shared__ char smem[];
    half_t* habs = (half_t*)smem;
    float2* vst  = (float2*)(smem + VST_OFF);
    float*  part = (float*) (smem + PART_OFF);
    float*  xsq  = (float*) (smem + XSQ_OFF);
    float*  dab  = (float*) (smem + DAB_OFF);
    float*  mpl  = (float*) (smem + MPL_OFF);
    float*  nz   = (float*) (smem + NZ_OFF);

    const int tid  = threadIdx.x;
    const int lane = tid & 63;
    const int w    = tid >> 6;
    const int b    = blockIdx.x & 63;          // XCD-local quartet mapping
    const int q    = blockIdx.x >> 6;
    const int j0   = q * ROWS;
    unsigned* qb   = bar + ((unsigned)b << 5);

    // ---------------- load: |H|^2 slice -> LDS fp16 (depth-2 pipeline) -----
    {
        const size_t gb = ((size_t)b * K + j0) * K;
        const f4* rp = (const f4*)(hre + gb);
        const f4* ip = (const f4*)(him + gb);
        f4 lr0[2], lr1[2], li0[2], li1[2];
        lr0[0] = __builtin_nontemporal_load(rp + tid * 2);
        lr1[0] = __builtin_nontemporal_load(rp + tid * 2 + 1);
        li0[0] = __builtin_nontemporal_load(ip + tid * 2);
        li1[0] = __builtin_nontemporal_load(ip + tid * 2 + 1);
#pragma unroll
        for (int i = 0; i < 8; ++i) {
            const int cur = i & 1, nxt = cur ^ 1;
            if (i < 7) {
                const int e4 = (i + 1) * (NT * 2) + tid * 2;
                lr0[nxt] = __builtin_nontemporal_load(rp + e4);
                lr1[nxt] = __builtin_nontemporal_load(rp + e4 + 1);
                li0[nxt] = __builtin_nontemporal_load(ip + e4);
                li1[nxt] = __builtin_nontemporal_load(ip + e4 + 1);
            }
            const f4 r0 = lr0[cur], r1 = lr1[cur];
            const f4 m0 = li0[cur], m1 = li1[cur];
            float s[8];
            s[0] = r0.x*r0.x + m0.x*m0.x; s[1] = r0.y*r0.y + m0.y*m0.y;
            s[2] = r0.z*r0.z + m0.z*m0.z; s[3] = r0.w*r0.w + m0.w*m0.w;
            s[4] = r1.x*r1.x + m1.x*m1.x; s[5] = r1.y*r1.y + m1.y*m1.y;
            s[6] = r1.z*r1.z + m1.z*m1.z; s[7] = r1.w*r1.w + m1.w*m1.w;
            half8 hh;
#pragma unroll
            for (int t = 0; t < 8; ++t) hh[t] = (_Float16)s[t];
            const int e = i * (NT * 8) + tid * 8;     // element 0..65535
            *(half8*)(habs + e) = hh;
            const int row  = e >> 9;                  // local row 0..127
            const int col0 = e & (K - 1);
            const int j    = j0 + row;                // diag at global col j
            if (j >= col0 && j < col0 + 8) dab[row] = s[j - col0];
        }
        if (tid < K) {
            float a = vre[b * K + tid], c = vim[b * K + tid];
            vst[tid] = make_float2(a, c);
            xsq[tid] = a * a + c * c;
            mpl[tid] = mp[b * K + tid];
        } else if (tid < K + ROWS) {
            nz[tid - K] = noise[b * K + j0 + (tid - K)];
        }
    }
    __syncthreads();

    for (int l = 0; l < NL; ++l) {
        const int buf = l & 1;
        // ---------------- P1: cov matvec + per-row algebra -----------------
        const f4 xa = ((const f4*)xsq)[lane * 2];
        const f4 xb = ((const f4*)xsq)[lane * 2 + 1];
        half8 h[8];
        float rs[8];
#pragma unroll
        for (int r = 0; r < 8; ++r) {
            h[r] = *(const half8*)(habs + ((w * 8 + r) * K + lane * 8));
            float acc = (float)h[r][0]*xa.x + (float)h[r][1]*xa.y +
                        (float)h[r][2]*xa.z + (float)h[r][3]*xa.w +
                        (float)h[r][4]*xb.x + (float)h[r][5]*xb.y +
                        (float)h[r][6]*xb.z + (float)h[r][7]*xb.w;
#pragma unroll
            for (int off = 32; off; off >>= 1) acc += __shfl_xor(acc, off, 64);
            rs[r] = acc;                              // all lanes hold row sum
        }
        float ulv_own = 0.f;
        if (lane < 8) {
            const int row = w * 8 + lane;
            const int j   = j0 + row;
            const int bj  = b * K + j;
            float s = lane==0?rs[0]:lane==1?rs[1]:lane==2?rs[2]:lane==3?rs[3]:
                      lane==4?rs[4]:lane==5?rs[5]:lane==6?rs[6]:rs[7];
            const float cov = s + nz[row];
            const float d2  = dab[row];
            const float A   = d2 * xsq[j];
            const float ww  = cov / (cov - A);        // w is real, > 0
            const float sc  = d2 * ww / cov;
            const float2 vv = vst[j];
            st_l3_2(&vtilde[buf * BK + bj], make_float2(sc * vv.x, sc * vv.y));
            ulv_own = A * ww / (cov * cov);           // |u|^2 |w|
        }
        float ulv[8];
#pragma unroll
        for (int r = 0; r < 8; ++r) ulv[r] = __shfl(ulv_own, r, 64);

        // ---------------- P2: transposed matvec, reuse h fragments ---------
        float pw[8];
#pragma unroll
        for (int t = 0; t < 8; ++t) {
            pw[t] = (float)h[0][t]*ulv[0] + (float)h[1][t]*ulv[1] +
                    (float)h[2][t]*ulv[2] + (float)h[3][t]*ulv[3] +
                    (float)h[4][t]*ulv[4] + (float)h[5][t]*ulv[5] +
                    (float)h[6][t]*ulv[6] + (float)h[7][t]*ulv[7];
        }
        float* pr = part + (w & 7) * K + lane * 8;
        if (w < 8) {
#pragma unroll
            for (int t = 0; t < 8; ++t) pr[t] = pw[t];
        }
        __syncthreads();
        if (w >= 8) {
#pragma unroll
            for (int t = 0; t < 8; ++t) pr[t] += pw[t];  // disjoint slots
        }
        __syncthreads();
        float s2 = 0.f;                               // own quartet partial
        if (tid < K) {
            s2 = part[tid]       + part[K + tid]   + part[2*K + tid] +
                 part[3*K + tid] + part[4*K + tid] + part[5*K + tid] +
                 part[6*K + tid] + part[7*K + tid];
            st_l3(&ulpart[(size_t)buf * (B*4*K) + ((size_t)(b*4 + q)) * K + tid],
                  s2);
        }
        quartet_barrier(qb, 4u * (unsigned)(l + 1));

        // ---------------- FIN: whole batch row (redundant x4) --------------
        if (tid < K) {
            const int k  = tid;
            const int bk = b * K + k;
            const float* up = ulpart + (size_t)buf * (B*4*K) + (size_t)(b*4) * K;
            float ul = s2;                            // own partial: registers
#pragma unroll
            for (int qq = 0; qq < 4; ++qq)
                if (qq != q) ul += ld_l3(up + qq * K + k);
            const float2 vt = ld_l3_2(&vtilde[buf * BK + bk]);
            const float p   = mpl[k];
            const float avt = sqrtf(vt.x*vt.x + vt.y*vt.y);
            const float mu  = fmaxf(avt / sqrtf(p) - ul, 0.f);
            const float inv = 1.f / (ul + mu);
            float ax = 0.f, ay = 0.f;
#pragma unroll
            for (int c = 0; c < C; ++c) {
                const float gre = ar_re[c] * inv + dl_re[c];
                const float gim = ar_im[c] * inv + dl_im[c];
                float zre = vt.x * gre - vt.y * gim;
                float zim = vt.x * gim + vt.y * gre;
                zre = fmaxf(zre, 0.f);                 // CReLU
                zim = fmaxf(zim, 0.f);
                ax += zre * rc_re[c] - zim * rc_im[c];
                ay += zre * rc_im[c] + zim * rc_re[c];
            }
            const float n2   = ax*ax + ay*ay;
            const float cur  = fmaxf(p, n2);
            const float corr = fminf(sqrtf(p / cur), 1.f);
            ax *= corr; ay *= corr;
            if ((k >> 7) == q)                          // owner writes out
                ((float2*)out)[(size_t)l * BK + bk] = make_float2(ax, ay);
            vst[k] = make_float2(ax, ay);
            xsq[k] = ax * ax + ay * ay;
        }
        __syncthreads();
    }
}

// ---------------------------------------------------------------------------
extern "C" void kernel_launch(void* const* d_in, const int* in_sizes, int n_in,
                              void* d_out, int out_size, void* d_ws, size_t ws_size,
                              hipStream_t stream) {
    const float* hre   = (const float*)d_in[0];
    const float* him   = (const float*)d_in[1];
    const float* noise = (const float*)d_in[2];
    const float* mp    = (const float*)d_in[3];
    const float* vre   = (const float*)d_in[4];
    const float* vim   = (const float*)d_in[5];
    const float* ar_re = (const float*)d_in[6];
    const float* ar_im = (const float*)d_in[7];
    const float* dl_re = (const float*)d_in[8];
    const float* dl_im = (const float*)d_in[9];
    const float* rc_re = (const float*)d_in[10];
    const float* rc_im = (const float*)d_in[11];
    float* out = (float*)d_out;

    char*     ws     = (char*)d_ws;
    float2*   vtilde = (float2*)ws;                               // 512 KB
    float*    ulpart = (float*)(ws + 2*(size_t)BK*8);             // 1 MB
    unsigned* bar    = (unsigned*)(ws + 2*(size_t)BK*8 + 2*(size_t)B*4*K*4);

    static bool attr_done = false;
    if (!attr_done) {
        hipFuncSetAttribute((const void*)k_all,
                            hipFuncAttributeMaxDynamicSharedMemorySize,
                            SMEM_BYTES);
        attr_done = true;
    }

    // monotonic barrier counters must be zero at kernel start on every replay
    hipMemsetAsync(bar, 0, B * 32 * sizeof(unsigned), stream);

    hipLaunchKernelGGL(k_all, dim3(GRID), dim3(NT), SMEM_BYTES, stream,
                       hre, him, noise, mp, vre, vim,
                       ar_re, ar_im, dl_re, dl_im, rc_re, rc_im,
                       vtilde, ulpart, bar, out);
}

// Round 5
// 188.639 us; speedup vs baseline: 1.8409x; 1.0219x over previous
//
#include <hip/hip_runtime.h>

#define B    64
#define K    512
#define C    4
#define NL   5
#define BK   (B*K)
#define ROWS 128            // rows of Habs2 per block
#define NT   1024           // threads per block (16 waves)
#define GRID (B*4)          // 256 blocks = 1 per CU

typedef _Float16 half_t;
typedef _Float16 half8 __attribute__((ext_vector_type(8)));
typedef float    f4    __attribute__((ext_vector_type(4)));

// ---- LDS layout (bytes). part oversized (36 slices, 16 used) so the block's
// LDS footprint >80 KiB -> hardware can place only 1 block/CU (even spread).
#define PART_OFF   0
#define VST_OFF    (36*K*4)              // float2[512]
#define XSQ_OFF    (VST_OFF + K*8)       // float[512]
#define MPL_OFF    (XSQ_OFF + K*4)       // float[512]
#define NZ_OFF     (MPL_OFF + K*4)       // float[128]
#define DAB_OFF    (NZ_OFF + ROWS*4)     // float[128]
#define RSB_OFF    (DAB_OFF + ROWS*4)    // float[128]
#define SMEM_BYTES (RSB_OFF + ROWS*4)    // 83456 B

// ---- L3-direct (bypass L1/L2) data ops: relaxed agent-scope atomics --------
__device__ __forceinline__ float ld_l3(const float* p) {
    return __uint_as_float(__hip_atomic_load((const unsigned*)p,
        __ATOMIC_RELAXED, __HIP_MEMORY_SCOPE_AGENT));
}
__device__ __forceinline__ void st_l3(float* p, float v) {
    __hip_atomic_store((unsigned*)p, __float_as_uint(v),
        __ATOMIC_RELAXED, __HIP_MEMORY_SCOPE_AGENT);
}
__device__ __forceinline__ void st_l3_2(float2* p, float2 v) {
    unsigned long long u = ((unsigned long long)__float_as_uint(v.y) << 32)
                         | (unsigned long long)__float_as_uint(v.x);
    __hip_atomic_store((unsigned long long*)p, u,
        __ATOMIC_RELAXED, __HIP_MEMORY_SCOPE_AGENT);
}
__device__ __forceinline__ float2 ld_l3_2(const float2* p) {
    unsigned long long u = __hip_atomic_load((const unsigned long long*)p,
        __ATOMIC_RELAXED, __HIP_MEMORY_SCOPE_AGENT);
    return make_float2(__uint_as_float((unsigned)(u & 0xffffffffu)),
                       __uint_as_float((unsigned)(u >> 32)));
}

// ---------------------------------------------------------------------------
// One persistent kernel, fully register-resident H-slices.
// Block (b = blockIdx&63, q = blockIdx>>6) owns rows j0..j0+127 of batch b.
// Thread fragment (fixed for the whole kernel): rows {16*i + w}, cols
// lane*8..lane*8+7, held as 8x half8 in VGPRs (filled during the HBM stream;
// layer-0 P1 dot fused into the stream in f32). No habs LDS tile at all.
// Per layer: P1 dot from regs -> rsbuf -> per-row algebra; P2 transposed
// matvec from regs -> single-pass 16-slice LDS reduce; fence-free monotonic
// quartet barrier (per-wave poll exit); FIN whole batch (redundant x4).
// Cross-block data via L3-direct ops; vtilde/ulpart double-buffered.
// ---------------------------------------------------------------------------
__global__ __launch_bounds__(NT, 4) void k_all(
    const float* __restrict__ hre,  const float* __restrict__ him,
    const float* __restrict__ noise,const float* __restrict__ mp,
    const float* __restrict__ vre,  const float* __restrict__ vim,
    const float* __restrict__ ar_re,const float* __restrict__ ar_im,
    const float* __restrict__ dl_re,const float* __restrict__ dl_im,
    const float* __restrict__ rc_re,const float* __restrict__ rc_im,
    float2* __restrict__ vtilde,    // [2][BK]
    float*  __restrict__ ulpart,    // [2][B*4][K]
    unsigned* __restrict__ bar,     // 64 quartets x 32 uints (128 B)
    float* __restrict__ out)        // [NL][BK][2]
{
    extern __shared__ char smem[];
    float*  part  = (float*) (smem + PART_OFF);
    float2* vst   = (float2*)(smem + VST_OFF);
    float*  xsq   = (float*) (smem + XSQ_OFF);
    float*  mpl   = (float*) (smem + MPL_OFF);
    float*  nz    = (float*) (smem + NZ_OFF);
    float*  dab   = (float*) (smem + DAB_OFF);
    float*  rsbuf = (float*) (smem + RSB_OFF);

    const int tid  = threadIdx.x;
    const int lane = tid & 63;
    const int w    = tid >> 6;
    const int b    = blockIdx.x & 63;
    const int q    = blockIdx.x >> 6;
    const int j0   = q * ROWS;
    unsigned* qb   = bar + ((unsigned)b << 5);

    // ---------------- init: v state, |v|^2, maxpow, noise -------------------
    if (tid < K) {
        float a = vre[b * K + tid], c2 = vim[b * K + tid];
        vst[tid] = make_float2(a, c2);
        xsq[tid] = a * a + c2 * c2;
        mpl[tid] = mp[b * K + tid];
    } else if (tid < K + ROWS) {
        nz[tid - K] = noise[b * K + j0 + (tid - K)];
    }
    __syncthreads();

    // ---------------- HBM stream -> register fragments + fused layer-0 P1 --
    half8 h[8];
    {
        const f4 xa = ((const f4*)xsq)[lane * 2];
        const f4 xb = ((const f4*)xsq)[lane * 2 + 1];
        const size_t gb = ((size_t)b * K + j0) * K;
        const f4* rp = (const f4*)(hre + gb);
        const f4* ip = (const f4*)(him + gb);
        f4 lr0[2], lr1[2], li0[2], li1[2];
        lr0[0] = __builtin_nontemporal_load(rp + tid * 2);
        lr1[0] = __builtin_nontemporal_load(rp + tid * 2 + 1);
        li0[0] = __builtin_nontemporal_load(ip + tid * 2);
        li1[0] = __builtin_nontemporal_load(ip + tid * 2 + 1);
#pragma unroll
        for (int i = 0; i < 8; ++i) {
            const int cur = i & 1, nxt = cur ^ 1;
            if (i < 7) {
                const int e4 = (i + 1) * (NT * 2) + tid * 2;
                lr0[nxt] = __builtin_nontemporal_load(rp + e4);
                lr1[nxt] = __builtin_nontemporal_load(rp + e4 + 1);
                li0[nxt] = __builtin_nontemporal_load(ip + e4);
                li1[nxt] = __builtin_nontemporal_load(ip + e4 + 1);
            }
            const f4 r0 = lr0[cur], r1 = lr1[cur];
            const f4 m0 = li0[cur], m1 = li1[cur];
            float s[8];
            s[0] = r0.x*r0.x + m0.x*m0.x; s[1] = r0.y*r0.y + m0.y*m0.y;
            s[2] = r0.z*r0.z + m0.z*m0.z; s[3] = r0.w*r0.w + m0.w*m0.w;
            s[4] = r1.x*r1.x + m1.x*m1.x; s[5] = r1.y*r1.y + m1.y*m1.y;
            s[6] = r1.z*r1.z + m1.z*m1.z; s[7] = r1.w*r1.w + m1.w*m1.w;
            half8 hh;
#pragma unroll
            for (int t = 0; t < 8; ++t) hh[t] = (_Float16)s[t];
            h[i] = hh;                                // fragment kept forever
            const int row  = i * 16 + w;              // local row 0..127
            const int col0 = lane * 8;
            const int j    = j0 + row;
            if (j >= col0 && j < col0 + 8) dab[row] = s[j - col0];
            // fused layer-0 P1 dot (f32 inputs, hidden under the stream)
            float acc = s[0]*xa.x + s[1]*xa.y + s[2]*xa.z + s[3]*xa.w +
                        s[4]*xb.x + s[5]*xb.y + s[6]*xb.z + s[7]*xb.w;
#pragma unroll
            for (int off = 32; off; off >>= 1) acc += __shfl_xor(acc, off, 64);
            if (lane == 0) rsbuf[row] = acc;          // own-wave read later
        }
    }

    for (int l = 0; l < NL; ++l) {
        const int buf = l & 1;
        // ---------------- P1 (layers >=1): dot from register fragments -----
        if (l > 0) {
            const f4 xa = ((const f4*)xsq)[lane * 2];
            const f4 xb = ((const f4*)xsq)[lane * 2 + 1];
#pragma unroll
            for (int r = 0; r < 8; ++r) {
                float acc = (float)h[r][0]*xa.x + (float)h[r][1]*xa.y +
                            (float)h[r][2]*xa.z + (float)h[r][3]*xa.w +
                            (float)h[r][4]*xb.x + (float)h[r][5]*xb.y +
                            (float)h[r][6]*xb.z + (float)h[r][7]*xb.w;
#pragma unroll
                for (int off = 32; off; off >>= 1) acc += __shfl_xor(acc, off, 64);
                if (lane == 0) rsbuf[r * 16 + w] = acc;
            }
        }
        // ---------------- per-row algebra: lane r<8 owns row 16*r + w ------
        float ulv_own = 0.f;
        if (lane < 8) {
            const int row = 16 * lane + w;
            const int j   = j0 + row;
            const int bj  = b * K + j;
            const float cov = rsbuf[row] + nz[row];
            const float d2  = dab[row];
            const float A   = d2 * xsq[j];
            const float ww  = cov / (cov - A);        // w is real, > 0
            const float sc  = d2 * ww / cov;
            const float2 vv = vst[j];
            st_l3_2(&vtilde[buf * BK + bj], make_float2(sc * vv.x, sc * vv.y));
            ulv_own = A * ww / (cov * cov);           // |u|^2 |w|
        }
        float ulv[8];
#pragma unroll
        for (int r = 0; r < 8; ++r) ulv[r] = __shfl(ulv_own, r, 64);

        // ---------------- P2: transposed matvec from register fragments ----
        float pw[8];
#pragma unroll
        for (int t = 0; t < 8; ++t) {
            pw[t] = (float)h[0][t]*ulv[0] + (float)h[1][t]*ulv[1] +
                    (float)h[2][t]*ulv[2] + (float)h[3][t]*ulv[3] +
                    (float)h[4][t]*ulv[4] + (float)h[5][t]*ulv[5] +
                    (float)h[6][t]*ulv[6] + (float)h[7][t]*ulv[7];
        }
        float* pr = part + w * K + lane * 8;          // 16 disjoint slices
#pragma unroll
        for (int t = 0; t < 8; ++t) pr[t] = pw[t];
        __syncthreads();                              // sync 1

        float s2 = 0.f;                               // own quartet partial
        if (tid < K) {
#pragma unroll
            for (int ws2 = 0; ws2 < 16; ++ws2) s2 += part[ws2 * K + tid];
            st_l3(&ulpart[(size_t)buf * (B*4*K) + ((size_t)(b*4 + q)) * K + tid],
                  s2);
        }
        __syncthreads();                              // sync 2: drain st_l3
        if (tid == 0)
            __hip_atomic_fetch_add(qb, 1u, __ATOMIC_RELAXED,
                                   __HIP_MEMORY_SCOPE_AGENT);
        if (lane == 0) {                              // per-wave poll exit
            const unsigned target = 4u * (unsigned)(l + 1);
            while (__hip_atomic_load(qb, __ATOMIC_RELAXED,
                                     __HIP_MEMORY_SCOPE_AGENT) < target)
                __builtin_amdgcn_s_sleep(2);
        }
        asm volatile("" ::: "memory");                // no hoisting past poll

        // ---------------- FIN: whole batch row (redundant x4) --------------
        if (tid < K) {
            const int k  = tid;
            const int bk = b * K + k;
            const float* up = ulpart + (size_t)buf * (B*4*K) + (size_t)(b*4) * K;
            const float2 vt = ld_l3_2(&vtilde[buf * BK + bk]);
            float ul = s2;                            // own partial: register
#pragma unroll
            for (int qq = 0; qq < 4; ++qq)
                if (qq != q) ul += ld_l3(up + qq * K + k);
            const float p   = mpl[k];
            const float avt = sqrtf(vt.x*vt.x + vt.y*vt.y);
            const float mu  = fmaxf(avt / sqrtf(p) - ul, 0.f);
            const float inv = 1.f / (ul + mu);
            float ax = 0.f, ay = 0.f;
#pragma unroll
            for (int c = 0; c < C; ++c) {
                const float gre = ar_re[c] * inv + dl_re[c];
                const float gim = ar_im[c] * inv + dl_im[c];
                float zre = vt.x * gre - vt.y * gim;
                float zim = vt.x * gim + vt.y * gre;
                zre = fmaxf(zre, 0.f);                 // CReLU
                zim = fmaxf(zim, 0.f);
                ax += zre * rc_re[c] - zim * rc_im[c];
                ay += zre * rc_im[c] + zim * rc_re[c];
            }
            const float n2   = ax*ax + ay*ay;
            const float cur  = fmaxf(p, n2);
            const float corr = fminf(sqrtf(p / cur), 1.f);
            ax *= corr; ay *= corr;
            if ((k >> 7) == q)                         // owner writes out
                ((float2*)out)[(size_t)l * BK + bk] = make_float2(ax, ay);
            vst[k] = make_float2(ax, ay);
            xsq[k] = ax * ax + ay * ay;
        }
        __syncthreads();                              // sync 3
    }
}

// ---------------------------------------------------------------------------
extern "C" void kernel_launch(void* const* d_in, const int* in_sizes, int n_in,
                              void* d_out, int out_size, void* d_ws, size_t ws_size,
                              hipStream_t stream) {
    const float* hre   = (const float*)d_in[0];
    const float* him   = (const float*)d_in[1];
    const float* noise = (const float*)d_in[2];
    const float* mp    = (const float*)d_in[3];
    const float* vre   = (const float*)d_in[4];
    const float* vim   = (const float*)d_in[5];
    const float* ar_re = (const float*)d_in[6];
    const float* ar_im = (const float*)d_in[7];
    const float* dl_re = (const float*)d_in[8];
    const float* dl_im = (const float*)d_in[9];
    const float* rc_re = (const float*)d_in[10];
    const float* rc_im = (const float*)d_in[11];
    float* out = (float*)d_out;

    char*     ws     = (char*)d_ws;
    float2*   vtilde = (float2*)ws;                               // 512 KB
    float*    ulpart = (float*)(ws + 2*(size_t)BK*8);             // 1 MB
    unsigned* bar    = (unsigned*)(ws + 2*(size_t)BK*8 + 2*(size_t)B*4*K*4);

    static bool attr_done = false;
    if (!attr_done) {
        hipFuncSetAttribute((const void*)k_all,
                            hipFuncAttributeMaxDynamicSharedMemorySize,
                            SMEM_BYTES);
        attr_done = true;
    }

    // monotonic barrier counters must be zero at kernel start on every replay
    hipMemsetAsync(bar, 0, B * 32 * sizeof(unsigned), stream);

    hipLaunchKernelGGL(k_all, dim3(GRID), dim3(NT), SMEM_BYTES, stream,
                       hre, him, noise, mp, vre, vim,
                       ar_re, ar_im, dl_re, dl_im, rc_re, rc_im,
                       vtilde, ulpart, bar, out);
}